// Round 1
// baseline (492.821 us; speedup 1.0000x reference)
//
#include <hip/hip_runtime.h>

#define NUM_USERS 80000
#define NUM_ITEMS 40000
#define NUM_NODES 120000
#define DIM 64
#define ALPHA_C 0.8f

typedef unsigned short u16;
typedef unsigned int u32;
typedef int   i2v __attribute__((ext_vector_type(2)));
typedef u32   u4v __attribute__((ext_vector_type(4)));
typedef float f4v __attribute__((ext_vector_type(4)));

// fp32 -> bf16 round-nearest-even
__device__ __forceinline__ u16 f2bf(float f) {
    union { float f; u32 i; } v;
    v.f = f;
    u32 i = v.i;
    u32 r = (i + 0x7FFFu + ((i >> 16) & 1u)) >> 16;
    return (u16)r;
}
__device__ __forceinline__ float lo_bf(u32 u) { return __uint_as_float(u << 16); }
__device__ __forceinline__ float hi_bf(u32 u) { return __uint_as_float(u & 0xffff0000u); }

// accumulate 8 bf16 (packed in uint4) * v into acc[8]
__device__ __forceinline__ void acc8(float* __restrict__ acc, float v, uint4 q) {
    const u32* p = (const u32*)&q;
#pragma unroll
    for (int k = 0; k < 4; ++k) {
        u32 u = p[k];
        acc[2 * k]     = fmaf(v, lo_bf(u), acc[2 * k]);
        acc[2 * k + 1] = fmaf(v, hi_bf(u), acc[2 * k + 1]);
    }
}

__device__ __forceinline__ uint4 ldrow(const u16* __restrict__ x, int c, int li) {
    return *((const uint4*)(x + (size_t)c * DIM) + li);
}

// ---------------------------------------------------------------------------
// Depth-4 software-pipelined segment gather. 8-lane group walks its segment.
// Per iteration: load edge-pair p, issue row gathers for pair p-2, consume
// pair p-4. Edge loads sit 2 iterations ahead of their gather so the vmcnt
// wait for addresses never drains the in-flight row gathers.
// PACKED: edges come as {col:int, val:f32} int2 stream (mev / merged graph).
// !PACKED: separate col[] / val[] arrays (path SpMM: col=p_col, val=exp_v).
// If SUMV, also accumulates the sum of val into *vsum.
// ---------------------------------------------------------------------------
template <bool SUMV, bool PACKED>
__device__ __forceinline__ void seg_pipe(const int* __restrict__ cp0,
                                         const float* __restrict__ vp0,
                                         const i2v* __restrict__ ep0,
                                         int start, int end,
                                         const u16* __restrict__ x,
                                         int li,
                                         float* __restrict__ acc,
                                         float* __restrict__ vsum) {
    const int n = end - start;
    const int* cp = nullptr;
    const float* vp = nullptr;
    const i2v* ep = nullptr;
    if constexpr (PACKED) { ep = ep0 + start; }
    else { cp = cp0 + start; vp = vp0 + start; }

    auto LDE = [&](int i, int& c, float& v) {
        if constexpr (PACKED) {
            i2v e = ep[i];
            c = e.x;
            v = __int_as_float(e.y);
        } else {
            c = cp[i];
            v = vp[i];
        }
    };

    float s = 0.f;
    const int np = n >> 1;
    if (np >= 4) {
        int ca0, ca1, cb0, cb1, cc0, cc1, cd0, cd1;
        float va0, va1, vb0, vb1, vc0, vc1, vd0, vd1;
        LDE(0, ca0, va0); LDE(1, ca1, va1);
        LDE(2, cb0, vb0); LDE(3, cb1, vb1);
        LDE(4, cc0, vc0); LDE(5, cc1, vc1);
        LDE(6, cd0, vd0); LDE(7, cd1, vd1);
        uint4 xa0 = ldrow(x, ca0, li), xa1 = ldrow(x, ca1, li);
        uint4 xb0 = ldrow(x, cb0, li), xb1 = ldrow(x, cb1, li);
        for (int p = 4; p < np; ++p) {
            // E: prefetch edge pair p (2 iterations ahead of its gather)
            int ce0, ce1; float ve0, ve1;
            LDE(2 * p, ce0, ve0); LDE(2 * p + 1, ce1, ve1);
            // G: issue row gathers for pair p-2 (edges arrived long ago)
            uint4 xc0 = ldrow(x, cc0, li);
            uint4 xc1 = ldrow(x, cc1, li);
            // C: consume pair p-4 (rows issued 2 iterations ago)
            acc8(acc, va0, xa0);
            acc8(acc, va1, xa1);
            if (SUMV) s += va0 + va1;
            // shift pipeline
            va0 = vb0; va1 = vb1; vb0 = vc0; vb1 = vc1; vc0 = vd0; vc1 = vd1;
            vd0 = ve0; vd1 = ve1;
            cc0 = cd0; cc1 = cd1; cd0 = ce0; cd1 = ce1;
            xa0 = xb0; xa1 = xb1; xb0 = xc0; xb1 = xc1;
        }
        // drain: pipe holds pairs A(rows xa), B(rows xb), C(cols cc), D(cols cd)
        uint4 xc0 = ldrow(x, cc0, li), xc1 = ldrow(x, cc1, li);
        uint4 xd0 = ldrow(x, cd0, li), xd1 = ldrow(x, cd1, li);
        acc8(acc, va0, xa0); acc8(acc, va1, xa1);
        if (SUMV) s += va0 + va1;
        acc8(acc, vb0, xb0); acc8(acc, vb1, xb1);
        if (SUMV) s += vb0 + vb1;
        acc8(acc, vc0, xc0); acc8(acc, vc1, xc1);
        if (SUMV) s += vc0 + vc1;
        acc8(acc, vd0, xd0); acc8(acc, vd1, xd1);
        if (SUMV) s += vd0 + vd1;
        if (n & 1) {
            int c; float v;
            LDE(n - 1, c, v);
            uint4 xq = ldrow(x, c, li);
            acc8(acc, v, xq);
            if (SUMV) s += v;
        }
    } else {
        for (int e = 0; e < n; ++e) {
            int c; float v;
            LDE(e, c, v);
            uint4 xq = ldrow(x, c, li);
            acc8(acc, v, xq);
            if (SUMV) s += v;
        }
    }
    if (SUMV) *vsum = s;
}

// ---------------------------------------------------------------------------
// K1: softmax over theta (6 elements) -> theta_w
// ---------------------------------------------------------------------------
__global__ void k_softmax_theta(const float* __restrict__ theta,
                                float* __restrict__ theta_w) {
    if (threadIdx.x == 0 && blockIdx.x == 0) {
        float m = -1e30f;
        for (int i = 0; i < 6; ++i) m = fmaxf(m, theta[i]);
        float e[6];
        float s = 0.f;
        for (int i = 0; i < 6; ++i) { e[i] = expf(theta[i] - m); s += e[i]; }
        for (int i = 0; i < 6; ++i) theta_w[i] = e[i] / s;
    }
}

// ---------------------------------------------------------------------------
// K2: exp_v[e] = exp(dot(p_counts[e,0:6], theta_w))   (no atomics)
// ---------------------------------------------------------------------------
__global__ void k_expv(const float* __restrict__ p_counts,
                       const float* __restrict__ theta_w,
                       float* __restrict__ exp_v, int E) {
    int i = blockIdx.x * blockDim.x + threadIdx.x;
    if (i >= E) return;
    const float* c = p_counts + (size_t)i * 6;
    float v = c[0] * theta_w[0] + c[1] * theta_w[1] + c[2] * theta_w[2] +
              c[3] * theta_w[3] + c[4] * theta_w[4] + c[5] * theta_w[5];
    exp_v[i] = expf(v);
}

// ---------------------------------------------------------------------------
// K3: all three CSR row_ptr arrays in one launch (rows sorted: np.unique)
// ---------------------------------------------------------------------------
__device__ __forceinline__ void lower_bound_ptr(const int* __restrict__ rows,
                                                int nnz, int r,
                                                int* __restrict__ ptr) {
    int lo = 0, hi = nnz;
    while (lo < hi) {
        int mid = (lo + hi) >> 1;
        if (rows[mid] < r) lo = mid + 1; else hi = mid;
    }
    ptr[r] = lo;
}

__global__ void k_row_ptr3(const int* __restrict__ rows_a, int nnz_a, int* __restrict__ pa,
                           const int* __restrict__ rows_b, int nnz_b, int* __restrict__ pb,
                           const int* __restrict__ rows_c, int nnz_c, int* __restrict__ pc) {
    int t = blockIdx.x * blockDim.x + threadIdx.x;
    int which = t / (NUM_NODES + 1);
    int r = t - which * (NUM_NODES + 1);
    if (which == 0) lower_bound_ptr(rows_a, nnz_a, r, pa);
    else if (which == 1) lower_bound_ptr(rows_b, nnz_b, r, pb);
    else if (which == 2) lower_bound_ptr(rows_c, nnz_c, r, pc);
}

// ---------------------------------------------------------------------------
// K4: convert user_emb || item_emb (fp32) -> bf16 table
// ---------------------------------------------------------------------------
__global__ void k_cvt(const float* __restrict__ user_emb,
                      const float* __restrict__ item_emb,
                      u16* __restrict__ emb16) {
    int i = blockIdx.x * blockDim.x + threadIdx.x;   // handles 4 floats
    size_t f = (size_t)i * 4;
    const size_t UTOT = (size_t)NUM_USERS * DIM;
    const size_t TOT = (size_t)NUM_NODES * DIM;
    if (f >= TOT) return;
    float4 v = (f < UTOT) ? *(const float4*)(user_emb + f)
                          : *(const float4*)(item_emb + (f - UTOT));
    ushort4 o;
    o.x = f2bf(v.x); o.y = f2bf(v.y); o.z = f2bf(v.z); o.w = f2bf(v.w);
    *(ushort4*)(emb16 + f) = o;
}

// ---------------------------------------------------------------------------
// K5: merge pos+neg CSR into one packed pre-scaled stream (one-time):
//     mev[rp_m[r] .. ] = {col, val} for pos edges, then {col, -ALPHA*val}
//     for neg edges. Exact same fp32 rounding as the old v*scale at use, and
//     the same per-row accumulation order (pos then neg), so layer outputs
//     are bitwise identical to the previous version.
// ---------------------------------------------------------------------------
__global__ void k_merge(const int* __restrict__ rp_p, const int* __restrict__ col_p,
                        const float* __restrict__ val_p,
                        const int* __restrict__ rp_n, const int* __restrict__ col_n,
                        const float* __restrict__ val_n,
                        i2v* __restrict__ mev, int* __restrict__ rp_m,
                        int nnz_total) {
    int t = blockIdx.x * blockDim.x + threadIdx.x;
    int row = t >> 3;
    if (row >= NUM_NODES) return;
    int li = threadIdx.x & 7;
    int sp = rp_p[row], np = rp_p[row + 1] - sp;
    int sn = rp_n[row], nn = rp_n[row + 1] - sn;
    int base = sp + sn;
    if (li == 0) {
        rp_m[row] = base;
        if (row == 0) rp_m[NUM_NODES] = nnz_total;
    }
    for (int i = li; i < np; i += 8) {
        i2v e;
        e.x = __builtin_nontemporal_load(col_p + sp + i);
        e.y = __float_as_int(__builtin_nontemporal_load(val_p + sp + i));
        __builtin_nontemporal_store(e, mev + base + i);
    }
    int b2 = base + np;
    for (int i = li; i < nn; i += 8) {
        i2v e;
        e.x = __builtin_nontemporal_load(col_n + sn + i);
        e.y = __float_as_int(-ALPHA_C * __builtin_nontemporal_load(val_n + sn + i));
        __builtin_nontemporal_store(e, mev + b2 + i);
    }
}

// ---------------------------------------------------------------------------
// K6: path SpMM with fused row-softmax. One 8-lane group per row.
// ---------------------------------------------------------------------------
__global__ void k_path(const u16* __restrict__ emb16,
                       const float* __restrict__ exp_v,
                       const int* __restrict__ rp,
                       const int* __restrict__ cols,
                       u16* __restrict__ e0) {
    int t = blockIdx.x * blockDim.x + threadIdx.x;
    int row = t >> 3;
    if (row >= NUM_NODES) return;
    int li = threadIdx.x & 7;
    int start = rp[row], end = rp[row + 1];

    float acc[8];
#pragma unroll
    for (int k = 0; k < 8; ++k) acc[k] = 0.f;
    float s = 0.f;

    seg_pipe<true, false>(cols, exp_v, nullptr, start, end, emb16, li, acc, &s);

    float inv = 1.0f / (s + 1e-12f);
    u32 o[4];
#pragma unroll
    for (int k = 0; k < 4; ++k)
        o[k] = (u32)f2bf(acc[2 * k] * inv) | ((u32)f2bf(acc[2 * k + 1] * inv) << 16);
    u4v vv; vv.x = o[0]; vv.y = o[1]; vv.z = o[2]; vv.w = o[3];
    __builtin_nontemporal_store(vv, (u4v*)(e0 + (size_t)row * DIM) + li);
}

// ---------------------------------------------------------------------------
// K7: one propagation layer over the merged pre-scaled stream.
//     acc = sum_merged val*x ; res = acc + ALPHA*e_in
//     FINAL=0: write res (bf16, nt) to e_out.
//     FINAL=1: out = 0.25*(e0 + e1 + e_in + res)  (fp32, nt, straight to d_out)
// ---------------------------------------------------------------------------
template <int FINAL>
__global__ void k_layer_t(const u16* __restrict__ e_in,
                          u16* __restrict__ e_out,
                          const u16* __restrict__ e0,
                          const u16* __restrict__ e1,
                          float* __restrict__ out,
                          const int* __restrict__ rp_m,
                          const i2v* __restrict__ mev) {
    int t = blockIdx.x * blockDim.x + threadIdx.x;
    int row = t >> 3;
    if (row >= NUM_NODES) return;
    int li = threadIdx.x & 7;

    float acc[8];
#pragma unroll
    for (int k = 0; k < 8; ++k) acc[k] = 0.f;

    seg_pipe<false, true>(nullptr, nullptr, mev, rp_m[row], rp_m[row + 1],
                          e_in, li, acc, nullptr);

    // own-row read after the walk (keeps walk register pressure < 64 VGPR)
    uint4 eq = *((const uint4*)(e_in + (size_t)row * DIM) + li);
    const u32* ep_ = (const u32*)&eq;
    float res[8];
#pragma unroll
    for (int k = 0; k < 4; ++k) {
        res[2 * k]     = acc[2 * k]     + ALPHA_C * lo_bf(ep_[k]);
        res[2 * k + 1] = acc[2 * k + 1] + ALPHA_C * hi_bf(ep_[k]);
    }

    if (FINAL) {
        u4v q0 = __builtin_nontemporal_load((const u4v*)(e0 + (size_t)row * DIM) + li);
        u4v q1 = __builtin_nontemporal_load((const u4v*)(e1 + (size_t)row * DIM) + li);
        float of[8];
#pragma unroll
        for (int k = 0; k < 4; ++k) {
            float lo = res[2 * k]     + lo_bf(ep_[k]) + lo_bf(q0[k]) + lo_bf(q1[k]);
            float hi = res[2 * k + 1] + hi_bf(ep_[k]) + hi_bf(q0[k]) + hi_bf(q1[k]);
            of[2 * k]     = 0.25f * lo;
            of[2 * k + 1] = 0.25f * hi;
        }
        f4v o0, o1;
        o0.x = of[0]; o0.y = of[1]; o0.z = of[2]; o0.w = of[3];
        o1.x = of[4]; o1.y = of[5]; o1.z = of[6]; o1.w = of[7];
        f4v* sp = (f4v*)(out + (size_t)row * DIM) + li * 2;
        __builtin_nontemporal_store(o0, sp);
        __builtin_nontemporal_store(o1, sp + 1);
    } else {
        u32 o[4];
#pragma unroll
        for (int k = 0; k < 4; ++k)
            o[k] = (u32)f2bf(res[2 * k]) | ((u32)f2bf(res[2 * k + 1]) << 16);
        u4v vv; vv.x = o[0]; vv.y = o[1]; vv.z = o[2]; vv.w = o[3];
        __builtin_nontemporal_store(vv, (u4v*)(e_out + (size_t)row * DIM) + li);
    }
}

// ---------------------------------------------------------------------------
extern "C" void kernel_launch(void* const* d_in, const int* in_sizes, int n_in,
                              void* d_out, int out_size, void* d_ws, size_t ws_size,
                              hipStream_t stream) {
    const float* user_emb = (const float*)d_in[0];
    const float* item_emb = (const float*)d_in[1];
    const float* theta    = (const float*)d_in[2];
    const int*   pos_row  = (const int*)d_in[3];
    const int*   pos_col  = (const int*)d_in[4];
    const float* pos_val  = (const float*)d_in[5];
    const int*   neg_row  = (const int*)d_in[6];
    const int*   neg_col  = (const int*)d_in[7];
    const float* neg_val  = (const float*)d_in[8];
    const int*   p_row    = (const int*)d_in[9];
    const int*   p_col    = (const int*)d_in[10];
    const float* p_counts = (const float*)d_in[11];
    const int E_pos  = in_sizes[3];
    const int E_neg  = in_sizes[6];
    const int E_path = in_sizes[9];

    // bump allocator over d_ws (256B aligned chunks)
    char* wsb = (char*)d_ws;
    size_t off = 0;
    auto alloc = [&](size_t bytes) -> void* {
        void* p = wsb + off;
        off = (off + bytes + 255) & ~(size_t)255;
        return p;
    };
    float* theta_w = (float*)alloc(6 * sizeof(float));
    float* exp_v   = (float*)alloc((size_t)E_path * sizeof(float));
    int*   rp_pos  = (int*)alloc((size_t)(NUM_NODES + 1) * sizeof(int));
    int*   rp_neg  = (int*)alloc((size_t)(NUM_NODES + 1) * sizeof(int));
    int*   rp_path = (int*)alloc((size_t)(NUM_NODES + 1) * sizeof(int));
    int*   rp_m    = (int*)alloc((size_t)(NUM_NODES + 1) * sizeof(int));
    i2v*   mev     = (i2v*)alloc((size_t)(E_pos + E_neg) * sizeof(i2v));
    u16*   emb16   = (u16*)alloc((size_t)NUM_NODES * DIM * sizeof(u16));
    u16*   e0      = (u16*)alloc((size_t)NUM_NODES * DIM * sizeof(u16));
    u16*   e1      = (u16*)alloc((size_t)NUM_NODES * DIM * sizeof(u16));
    u16*   e2      = emb16;   // emb16 is dead after k_path; reuse for e2
    float* outp    = (float*)d_out;

    k_softmax_theta<<<1, 64, 0, stream>>>(theta, theta_w);
    k_expv<<<(E_path + 255) / 256, 256, 0, stream>>>(p_counts, theta_w, exp_v, E_path);

    int total_rp = 3 * (NUM_NODES + 1);
    k_row_ptr3<<<(total_rp + 255) / 256, 256, 0, stream>>>(
        pos_row, E_pos, rp_pos, neg_row, E_neg, rp_neg, p_row, E_path, rp_path);

    int cvt_threads = (NUM_NODES * DIM) / 4;
    k_cvt<<<(cvt_threads + 255) / 256, 256, 0, stream>>>(user_emb, item_emb, emb16);

    // one 8-lane group per row: 32 rows per 256-thread block
    int row_blocks = (NUM_NODES + 31) / 32;  // 3750

    k_merge<<<row_blocks, 256, 0, stream>>>(rp_pos, pos_col, pos_val,
                                            rp_neg, neg_col, neg_val,
                                            mev, rp_m, E_pos + E_neg);

    k_path<<<row_blocks, 256, 0, stream>>>(emb16, exp_v, rp_path, p_col, e0);
    k_layer_t<0><<<row_blocks, 256, 0, stream>>>(e0, e1, nullptr, nullptr, nullptr,
                                                 rp_m, mev);
    k_layer_t<0><<<row_blocks, 256, 0, stream>>>(e1, e2, nullptr, nullptr, nullptr,
                                                 rp_m, mev);
    k_layer_t<1><<<row_blocks, 256, 0, stream>>>(e2, nullptr, e0, e1, outp,
                                                 rp_m, mev);
}